// Round 3
// baseline (208.644 us; speedup 1.0000x reference)
//
#include <hip/hip_runtime.h>
#include <stdint.h>

#define NEGV -1.0e9f
#define EPSV 1e-12f

typedef __attribute__((ext_vector_type(8))) short bf16x8;
typedef __attribute__((ext_vector_type(4))) float f32x4;

struct __align__(8) US4 { unsigned short a, b, c, d; };

__device__ __forceinline__ unsigned int f2bf(float f) {
  unsigned int u = __builtin_bit_cast(unsigned int, f);
  u = u + 0x7FFFu + ((u >> 16) & 1u);   // round-to-nearest-even
  return u >> 16;
}

// RNE pack of two f32 -> packed bf16x2 in one VALU inst (same bits as f2bf pair;
// inputs are post-relu finite so NaN behavior is irrelevant).
__device__ __forceinline__ unsigned int cvt_pk_bf16(float lo, float hi) {
  unsigned int r;
  asm("v_cvt_pk_bf16_f32 %0, %1, %2" : "=v"(r) : "v"(lo), "v"(hi));
  return r;
}

// ---------------- k_prep: one launch, three independent jobs
__global__ __launch_bounds__(256) void k_prep(
    const float* __restrict__ state, const float* __restrict__ w1,
    const float* __restrict__ b1, const float* __restrict__ emb_w,
    const float* __restrict__ emb_b, const float* __restrict__ w2,
    float* __restrict__ W1e, float* __restrict__ sb,
    unsigned short* __restrict__ W2t) {
  const int blk = blockIdx.x;
  const int tid = threadIdx.x;
  if (blk < 4) {
    const int j = blk * 256 + tid;
    float a0 = 0.f, a1 = 0.f, a2 = 0.f, a3 = 0.f, a4 = 0.f;
    for (int e = 0; e < 256; ++e) {
      const float w = w1[(size_t)(512 + e) * 1024 + j];
      a0 += emb_w[0 * 256 + e] * w;
      a1 += emb_w[1 * 256 + e] * w;
      a2 += emb_w[2 * 256 + e] * w;
      a3 += emb_w[3 * 256 + e] * w;
      a4 += emb_w[4 * 256 + e] * w;
    }
    W1e[0 * 1024 + j] = a0;
    W1e[1 * 1024 + j] = a1;
    W1e[2 * 1024 + j] = a2;
    W1e[3 * 1024 + j] = a3;
    W1e[4 * 1024 + j] = a4;
  } else if (blk < 516) {
    const int blk2 = blk - 4;
    const int b = blk2 >> 2;
    const int j = (blk2 & 3) * 256 + tid;
    float acc = b1[j];
    for (int e = 0; e < 256; ++e)
      acc += emb_b[e] * w1[(size_t)(512 + e) * 1024 + j];
    const float* st = state + (size_t)b * 512;
    for (int s = 0; s < 512; ++s) acc += st[s] * w1[(size_t)s * 1024 + j];
    sb[(size_t)b * 1024 + j] = acc;
  } else {
    __shared__ float tile[64][65];
    const int blk2 = blk - 516;
    const int gn = blk2 & 15, gk = blk2 >> 4;
    const int c = tid & 63, w = tid >> 6;
#pragma unroll
    for (int i = 0; i < 16; ++i) {
      const int r = i * 4 + w;
      tile[r][c] = w2[(size_t)(gk * 64 + r) * 1024 + gn * 64 + c];
    }
    __syncthreads();
#pragma unroll
    for (int i = 0; i < 16; ++i) {
      const int r = i * 4 + w;
      W2t[(size_t)(gn * 64 + r) * 1024 + gk * 64 + c] = (unsigned short)f2bf(tile[c][r]);
    }
  }
}

// ---------------- k_gemm: producer/consumer fused h1+GEMM.
// 256x256 tile, BK=32, 12 waves: 8 consumer (2Mx4N, pure ds_read+MFMA) +
// 4 producer (h1 by VALU -> swizzled ds_write A; B via global_load_lds).
// R14: R13's counters showed no pipe above ~45% (MFMA 35.5, LDS ~45, prod
// VALU 13) — the residual ~50% was barrier serialization with 1 block/CU
// (LDS 128KB). BK 64->32 halves LDS to 64KB -> 2 blocks/CU; barriers of one
// block are filled by the other block's MFMAs (m114 mechanism). Wave-level
// FLOP-per-ds_read is invariant (one b128 A read feeds one full K=32 MFMA).
// Swizzle: 4 chunks/row, position = c ^ ((row>>1)&3) (same 0-conflict
// distribution as the BK=64 8-chunk XOR, verified by bank enumeration).
__global__ __launch_bounds__(768, 2) void k_gemm(
    const float* __restrict__ tf, const float* __restrict__ sbm,
    const float* __restrict__ W1em, const unsigned short* __restrict__ W2t,
    const float* __restrict__ b2, const float* __restrict__ w3,
    float* __restrict__ partial) {
  __shared__ unsigned short As[2][8192];   // [buf][256 rows][32 k] swizzled
  __shared__ unsigned short Bs[2][8192];   // [buf][256 cols][32 k] swizzled

  const int bid = blockIdx.x;
  const int swz = (bid & 7) * 128 + (bid >> 3);   // XCD swizzle (1024 % 8 == 0)
  const int bx = swz >> 2, by = swz & 3;
  const int row0 = bx << 8, col0 = by << 8;
  const int bb = row0 >> 9;                       // batch (256-row tile, no straddle)

  const int tid = threadIdx.x, lane = tid & 63, wid = tid >> 6;

  if (wid < 8) {
    // ================= CONSUMER =================
    const int wr = wid >> 2, wc = wid & 3;
    const int lm = lane & 15, lg = lane >> 4;
    const int aoff = (wr * 128 + lm) * 32;        // + m*512 + s
    const int boff = (wc * 64 + lm) * 32;         // + n*512 + s
    const int s = ((lg ^ ((lm >> 1) & 3)) << 3);  // swizzled k-chunk (elems)

    f32x4 acc[8][4];
#pragma unroll
    for (int m = 0; m < 8; ++m)
#pragma unroll
      for (int n = 0; n < 4; ++n) acc[m][n] = (f32x4){0.f, 0.f, 0.f, 0.f};

    __syncthreads();   // matches producer prologue (tile 0 ready)

#pragma unroll 1
    for (int t = 0; t < 32; ++t) {
      const unsigned short* Ad = As[t & 1];
      const unsigned short* Bd = Bs[t & 1];
      bf16x8 bk[4];
      bf16x8 ap[2][2];   // rotating A-pair slots; all indices compile-time
#pragma unroll
      for (int n = 0; n < 4; ++n) bk[n] = *(const bf16x8*)(Bd + boff + n * 512 + s);
      ap[0][0] = *(const bf16x8*)(Ad + aoff + 0 * 512 + s);
      ap[0][1] = *(const bf16x8*)(Ad + aoff + 1 * 512 + s);
      __builtin_amdgcn_s_setprio(1);
#pragma unroll
      for (int G = 0; G < 4; ++G) {          // 4 groups of (2 m-rows x 4 n)
        const int cur = G & 1, nxt = cur ^ 1;
        if (G < 3) {
          ap[nxt][0] = *(const bf16x8*)(Ad + aoff + (2 * G + 2) * 512 + s);
          ap[nxt][1] = *(const bf16x8*)(Ad + aoff + (2 * G + 3) * 512 + s);
        }
#pragma unroll
        for (int n = 0; n < 4; ++n)
          acc[2 * G][n] = __builtin_amdgcn_mfma_f32_16x16x32_bf16(
              ap[cur][0], bk[n], acc[2 * G][n], 0, 0, 0);
#pragma unroll
        for (int n = 0; n < 4; ++n)
          acc[2 * G + 1][n] = __builtin_amdgcn_mfma_f32_16x16x32_bf16(
              ap[cur][1], bk[n], acc[2 * G + 1][n], 0, 0, 0);
      }
      __builtin_amdgcn_s_setprio(0);
      __syncthreads();   // tile boundary
    }

    // ---- epilogue: partial[row][by*4+wc] = sum_cols relu(acc + b2[col]) * w3[col]
    float b2v[4], w3v[4];
#pragma unroll
    for (int n = 0; n < 4; ++n) {
      const int col = col0 + wc * 64 + n * 16 + lm;
      b2v[n] = b2[col];
      w3v[n] = w3[col];
    }
#pragma unroll
    for (int m = 0; m < 8; ++m) {
#pragma unroll
      for (int r = 0; r < 4; ++r) {
        float v = 0.f;
#pragma unroll
        for (int n = 0; n < 4; ++n) {
          float h = acc[m][n][r] + b2v[n];
          h = fmaxf(h, 0.f);
          v += h * w3v[n];
        }
        v += __shfl_xor(v, 1, 16);
        v += __shfl_xor(v, 2, 16);
        v += __shfl_xor(v, 4, 16);
        v += __shfl_xor(v, 8, 16);
        if (lm == 0)
          partial[(size_t)(row0 + wr * 128 + m * 16 + lg * 4 + r) * 16 + by * 4 + wc] = v;
      }
    }
  } else {
    // ================= PRODUCER =================
    const int pt = tid - 512;               // 0..255
    const int pw = pt >> 6;                 // producer wave 0..3
    const int pc = (pt & 3) << 3;           // 8-col block within K-tile (0..24)
    const int prb = pt >> 2;                // 0..63; rows prb + 64j, j=0..3
    const int aph = (((pt & 3) ^ ((prb >> 1) & 3)) << 3);   // swizzled chunk (elems)
    // B staging: per l, 16 cols of 64B; dest linear = base + lane*16B.
    // col = pw*64 + l*16 + (lane>>2); within-col chunk position = lane&3;
    // source chunk = (lane&3) ^ swz(col), swz(col) = (col>>1)&3 = (lane>>3)&3.
    const int bcol = (lane >> 2);
    const int bscol = (((lane & 3) ^ ((lane >> 3) & 3)) << 3);

    // tf rows -> registers (4 rows x 5)
    float ptf[4][5];
#pragma unroll
    for (int j = 0; j < 4; ++j) {
      const float* f = tf + (size_t)(row0 + prb + 64 * j) * 5;
#pragma unroll
      for (int i = 0; i < 5; ++i) ptf[j][i] = f[i];
    }

    const float* sbp = sbm + (size_t)bb * 1024;

#define PRODUCE(kt, d)                                                         \
    {                                                                          \
      _Pragma("unroll")                                                        \
      for (int l = 0; l < 4; ++l)                                              \
        __builtin_amdgcn_global_load_lds(                                      \
            (const __attribute__((address_space(1))) void*)(                   \
                W2t + (size_t)(col0 + pw * 64 + l * 16 + bcol) * 1024 + (kt) * 32 + bscol), \
            (__attribute__((address_space(3))) void*)(                         \
                Bs[d] + (pw * 64 + l * 16) * 32), 16, 0, 0);                   \
      const int kb = (kt) * 32 + pc;                                           \
      const float4 sa = *(const float4*)(sbp + kb);                            \
      const float4 sbv = *(const float4*)(sbp + kb + 4);                       \
      float4 wa[5], wb[5];                                                     \
      _Pragma("unroll")                                                        \
      for (int i = 0; i < 5; ++i) {                                            \
        wa[i] = *(const float4*)(W1em + i * 1024 + kb);                        \
        wb[i] = *(const float4*)(W1em + i * 1024 + kb + 4);                    \
      }                                                                        \
      _Pragma("unroll")                                                        \
      for (int j = 0; j < 4; ++j) {                                            \
        const float f0 = ptf[j][0], f1 = ptf[j][1], f2 = ptf[j][2],            \
                    f3 = ptf[j][3], f4 = ptf[j][4];                            \
        float h0 = fmaf(f4, wa[4].x, fmaf(f3, wa[3].x, fmaf(f2, wa[2].x, fmaf(f1, wa[1].x, fmaf(f0, wa[0].x, sa.x))))); \
        float h1 = fmaf(f4, wa[4].y, fmaf(f3, wa[3].y, fmaf(f2, wa[2].y, fmaf(f1, wa[1].y, fmaf(f0, wa[0].y, sa.y))))); \
        float h2 = fmaf(f4, wa[4].z, fmaf(f3, wa[3].z, fmaf(f2, wa[2].z, fmaf(f1, wa[1].z, fmaf(f0, wa[0].z, sa.z))))); \
        float h3 = fmaf(f4, wa[4].w, fmaf(f3, wa[3].w, fmaf(f2, wa[2].w, fmaf(f1, wa[1].w, fmaf(f0, wa[0].w, sa.w))))); \
        float h4 = fmaf(f4, wb[4].x, fmaf(f3, wb[3].x, fmaf(f2, wb[2].x, fmaf(f1, wb[1].x, fmaf(f0, wb[0].x, sbv.x))))); \
        float h5 = fmaf(f4, wb[4].y, fmaf(f3, wb[3].y, fmaf(f2, wb[2].y, fmaf(f1, wb[1].y, fmaf(f0, wb[0].y, sbv.y))))); \
        float h6 = fmaf(f4, wb[4].z, fmaf(f3, wb[3].z, fmaf(f2, wb[2].z, fmaf(f1, wb[1].z, fmaf(f0, wb[0].z, sbv.z))))); \
        float h7 = fmaf(f4, wb[4].w, fmaf(f3, wb[3].w, fmaf(f2, wb[2].w, fmaf(f1, wb[1].w, fmaf(f0, wb[0].w, sbv.w))))); \
        h0 = fmaxf(h0, 0.f); h1 = fmaxf(h1, 0.f); h2 = fmaxf(h2, 0.f); h3 = fmaxf(h3, 0.f); \
        h4 = fmaxf(h4, 0.f); h5 = fmaxf(h5, 0.f); h6 = fmaxf(h6, 0.f); h7 = fmaxf(h7, 0.f); \
        uint4 pk;                                                              \
        pk.x = cvt_pk_bf16(h0, h1);                                            \
        pk.y = cvt_pk_bf16(h2, h3);                                            \
        pk.z = cvt_pk_bf16(h4, h5);                                            \
        pk.w = cvt_pk_bf16(h6, h7);                                            \
        *(uint4*)&As[d][(prb + 64 * j) * 32 + aph] = pk;                       \
      }                                                                        \
    }

    PRODUCE(0, 0);
    __syncthreads();   // vm+lgkm drained by syncthreads semantics; tile 0 ready
#pragma unroll 1
    for (int t = 0; t < 32; ++t) {
      if (t < 31) PRODUCE(t + 1, (t + 1) & 1);
      __syncthreads();
    }
#undef PRODUCE
  }
}

// ---------------- k_softmax: fused utils-reduction + nested-logit softmax
__global__ __launch_bounds__(256) void k_softmax(
    const float* __restrict__ partial, const float* __restrict__ b3,
    const int* __restrict__ nids, const int* __restrict__ mask,
    const float* __restrict__ etas, float* __restrict__ utils_out,
    float* __restrict__ p_task, float* __restrict__ p_nest) {
  const int b = blockIdx.x, tid = threadIdx.x;
  const int lane = tid & 63, wv = tid >> 6;
  __shared__ float smax[4][4];
  __shared__ int scnt[4][4];
  __shared__ float ssum[4][4];
  __shared__ float sred[4];
  __shared__ int sredi[4];

  const size_t base = (size_t)b * 512;
  const float b3v = b3[0];
  float uraw[2];
#pragma unroll
  for (int k = 0; k < 2; ++k) {
    const size_t row = base + tid + k * 256;
    const float4* p = (const float4*)(partial + row * 16);
    const float4 pa = p[0], pb = p[1], pc = p[2], pd = p[3];
    uraw[k] = b3v + pa.x + pa.y + pa.z + pa.w + pb.x + pb.y + pb.z + pb.w +
              pc.x + pc.y + pc.z + pc.w + pd.x + pd.y + pd.z + pd.w;
  }
  const int n0 = nids[base + tid], n1 = nids[base + 256 + tid];
  const bool m0 = mask[base + tid] != 0, m1 = mask[base + 256 + tid] != 0;
  const float u0 = m0 ? uraw[0] : NEGV;
  const float u1 = m1 ? uraw[1] : NEGV;
  utils_out[base + tid] = u0;
  utils_out[base + 256 + tid] = u1;
  const float eta[4] = {etas[0], etas[1], etas[2], etas[3]};

  float lmax[4]; int lcnt[4];
#pragma unroll
  for (int m = 0; m < 4; ++m) {
    const bool e0 = m0 && (n0 == m), e1 = m1 && (n1 == m);
    lmax[m] = fmaxf(e0 ? u0 : -INFINITY, e1 ? u1 : -INFINITY);
    lcnt[m] = (int)e0 + (int)e1;
  }
#pragma unroll
  for (int m = 0; m < 4; ++m)
#pragma unroll
    for (int off = 32; off >= 1; off >>= 1) {
      lmax[m] = fmaxf(lmax[m], __shfl_xor(lmax[m], off));
      lcnt[m] += __shfl_xor(lcnt[m], off);
    }
  if (lane == 0) {
#pragma unroll
    for (int m = 0; m < 4; ++m) { smax[wv][m] = lmax[m]; scnt[wv][m] = lcnt[m]; }
  }
  __syncthreads();
  float mval[4]; bool ne[4];
#pragma unroll
  for (int m = 0; m < 4; ++m) {
    const float mx = fmaxf(fmaxf(smax[0][m], smax[1][m]), fmaxf(smax[2][m], smax[3][m]));
    const int c = scnt[0][m] + scnt[1][m] + scnt[2][m] + scnt[3][m];
    ne[m] = c > 0;
    mval[m] = ne[m] ? mx : 0.f;
  }
  float lsum[4];
#pragma unroll
  for (int m = 0; m < 4; ++m) {
    float s = 0.f;
    if (m0 && n0 == m) s += expf((u0 - mval[m]) / eta[m]);
    if (m1 && n1 == m) s += expf((u1 - mval[m]) / eta[m]);
    lsum[m] = s;
  }
#pragma unroll
  for (int m = 0; m < 4; ++m)
#pragma unroll
    for (int off = 32; off >= 1; off >>= 1) lsum[m] += __shfl_xor(lsum[m], off);
  if (lane == 0) {
#pragma unroll
    for (int m = 0; m < 4; ++m) ssum[wv][m] = lsum[m];
  }
  __syncthreads();
  float sums[4], U[4];
#pragma unroll
  for (int m = 0; m < 4; ++m) {
    const float s = ssum[0][m] + ssum[1][m] + ssum[2][m] + ssum[3][m];
    sums[m] = fmaxf(s, EPSV);
    U[m] = ne[m] ? (mval[m] + eta[m] * logf(sums[m])) : NEGV;
  }
  const float mU = fmaxf(fmaxf(U[0], U[1]), fmaxf(U[2], U[3]));
  float pe[4], pes = 0.f;
#pragma unroll
  for (int m = 0; m < 4; ++m) { pe[m] = expf(U[m] - mU); pes += pe[m]; }
  float pn[4];
#pragma unroll
  for (int m = 0; m < 4; ++m) pn[m] = pe[m] / pes;
  if (tid == 0) {
#pragma unroll
    for (int m = 0; m < 4; ++m) p_nest[(size_t)b * 4 + m] = pn[m];
  }
  float pt[2];
  const float uu[2] = {u0, u1};
  const int nn[2] = {n0, n1};
  const bool mm[2] = {m0, m1};
#pragma unroll
  for (int k = 0; k < 2; ++k) {
    const bool valid = mm[k] && nn[k] >= 0 && nn[k] < 4;
    float mt = 0.f, st = 1.f, pnt = 0.f, et = 1.f;
#pragma unroll
    for (int m = 0; m < 4; ++m)
      if (nn[k] == m) { mt = mval[m]; st = sums[m]; pnt = pn[m]; et = eta[m]; }
    pt[k] = valid ? pnt * expf((uu[k] - mt) / et) / st : 0.f;
  }
  float lp = pt[0] + pt[1];
  int lmk = (int)m0 + (int)m1;
#pragma unroll
  for (int off = 32; off >= 1; off >>= 1) {
    lp += __shfl_xor(lp, off);
    lmk += __shfl_xor(lmk, off);
  }
  if (lane == 0) { sred[wv] = lp; sredi[wv] = lmk; }
  __syncthreads();
  const float sumpt = sred[0] + sred[1] + sred[2] + sred[3];
  const int nmask = sredi[0] + sredi[1] + sredi[2] + sredi[3];
  const bool fallback = (nmask > 0) && (sumpt <= EPSV);
  if (fallback) {
    const float uni = 1.f / (float)(nmask > 0 ? nmask : 1);
    pt[0] = m0 ? uni : pt[0];
    pt[1] = m1 ? uni : pt[1];
  }
  p_task[base + tid] = pt[0];
  p_task[base + 256 + tid] = pt[1];
}

extern "C" void kernel_launch(void* const* d_in, const int* in_sizes, int n_in,
                              void* d_out, int out_size, void* d_ws, size_t ws_size,
                              hipStream_t stream) {
  const float* state = (const float*)d_in[0];
  const float* tf = (const float*)d_in[1];
  const int* nids = (const int*)d_in[2];
  const int* mask = (const int*)d_in[3];
  const float* emb_w = (const float*)d_in[4];
  const float* emb_b = (const float*)d_in[5];
  const float* w1 = (const float*)d_in[6];
  const float* b1 = (const float*)d_in[7];
  const float* w2 = (const float*)d_in[8];
  const float* b2 = (const float*)d_in[9];
  const float* w3 = (const float*)d_in[10];
  const float* b3 = (const float*)d_in[11];
  const float* etas = (const float*)d_in[12];

  float* out = (float*)d_out;
  float* utils_out = out;            // 65536
  float* p_task = out + 65536;       // 65536
  float* p_nest = out + 131072;      // 512

  char* ws = (char*)d_ws;
  unsigned short* W2t = (unsigned short*)ws; ws += 1024ull * 1024 * 2;    // 2 MB
  float* partial = (float*)ws;               ws += 65536ull * 16 * 4;     // 4 MB
  float* W1e = (float*)ws;                   ws += 5 * 1024 * 4;
  float* sb = (float*)ws;                    ws += 128 * 1024 * 4;

  k_prep<<<772, 256, 0, stream>>>(state, w1, b1, emb_w, emb_b, w2, W1e, sb, W2t);
  k_gemm<<<1024, 768, 0, stream>>>(tf, sb, W1e, W2t, b2, w3, partial);
  k_softmax<<<128, 256, 0, stream>>>(partial, b3, nids, mask, etas,
                                     utils_out, p_task, p_nest);
}

// Round 4
// 180.848 us; speedup vs baseline: 1.1537x; 1.1537x over previous
//
#include <hip/hip_runtime.h>
#include <stdint.h>

#define NEGV -1.0e9f
#define EPSV 1e-12f

typedef __attribute__((ext_vector_type(8))) short bf16x8;
typedef __attribute__((ext_vector_type(4))) float f32x4;

struct __align__(8) US4 { unsigned short a, b, c, d; };

__device__ __forceinline__ unsigned int f2bf(float f) {
  unsigned int u = __builtin_bit_cast(unsigned int, f);
  u = u + 0x7FFFu + ((u >> 16) & 1u);   // round-to-nearest-even
  return u >> 16;
}

// RNE pack of two f32 -> packed bf16x2 in one VALU inst (same bits as f2bf pair;
// inputs are post-relu finite so NaN behavior is irrelevant).
__device__ __forceinline__ unsigned int cvt_pk_bf16(float lo, float hi) {
  unsigned int r;
  asm("v_cvt_pk_bf16_f32 %0, %1, %2" : "=v"(r) : "v"(lo), "v"(hi));
  return r;
}

// ---------------- k_prep: one launch, three independent jobs
__global__ __launch_bounds__(256) void k_prep(
    const float* __restrict__ state, const float* __restrict__ w1,
    const float* __restrict__ b1, const float* __restrict__ emb_w,
    const float* __restrict__ emb_b, const float* __restrict__ w2,
    float* __restrict__ W1e, float* __restrict__ sb,
    unsigned short* __restrict__ W2t) {
  const int blk = blockIdx.x;
  const int tid = threadIdx.x;
  if (blk < 4) {
    const int j = blk * 256 + tid;
    float a0 = 0.f, a1 = 0.f, a2 = 0.f, a3 = 0.f, a4 = 0.f;
    for (int e = 0; e < 256; ++e) {
      const float w = w1[(size_t)(512 + e) * 1024 + j];
      a0 += emb_w[0 * 256 + e] * w;
      a1 += emb_w[1 * 256 + e] * w;
      a2 += emb_w[2 * 256 + e] * w;
      a3 += emb_w[3 * 256 + e] * w;
      a4 += emb_w[4 * 256 + e] * w;
    }
    W1e[0 * 1024 + j] = a0;
    W1e[1 * 1024 + j] = a1;
    W1e[2 * 1024 + j] = a2;
    W1e[3 * 1024 + j] = a3;
    W1e[4 * 1024 + j] = a4;
  } else if (blk < 516) {
    const int blk2 = blk - 4;
    const int b = blk2 >> 2;
    const int j = (blk2 & 3) * 256 + tid;
    float acc = b1[j];
    for (int e = 0; e < 256; ++e)
      acc += emb_b[e] * w1[(size_t)(512 + e) * 1024 + j];
    const float* st = state + (size_t)b * 512;
    for (int s = 0; s < 512; ++s) acc += st[s] * w1[(size_t)s * 1024 + j];
    sb[(size_t)b * 1024 + j] = acc;
  } else {
    __shared__ float tile[64][65];
    const int blk2 = blk - 516;
    const int gn = blk2 & 15, gk = blk2 >> 4;
    const int c = tid & 63, w = tid >> 6;
#pragma unroll
    for (int i = 0; i < 16; ++i) {
      const int r = i * 4 + w;
      tile[r][c] = w2[(size_t)(gk * 64 + r) * 1024 + gn * 64 + c];
    }
    __syncthreads();
#pragma unroll
    for (int i = 0; i < 16; ++i) {
      const int r = i * 4 + w;
      W2t[(size_t)(gn * 64 + r) * 1024 + gk * 64 + c] = (unsigned short)f2bf(tile[c][r]);
    }
  }
}

// ---------------- k_gemm: producer/consumer fused h1+GEMM.
// 256x256 tile, BK=64, 12 waves: 8 consumer (2Mx4N, pure ds_read+MFMA, no VMEM)
// + 4 producer (h1 by VALU -> swizzled ds_write A; B via global_load_lds).
// Double-buffered LDS (128 KB), ONE __syncthreads per K-tile.
// OCCUPANCY MODEL (R14 lesson): unified regfile ~512/SIMD pins residency at
// 2 consumers (128 acc + ~80 arch) + 1 producer (~80) = ~496/SIMD. A second
// block can NEVER fit — don't chase occupancy; chase intra-SIMD pipe overlap.
// R15: R13/R14 counters showed MFMA (~39%) + LDS (~45%) ALTERNATE instead of
// overlapping — consumer waves run in barrier-lockstep, so read-bursts and
// MFMA-bursts coincide. Fix: K-half stagger. Waves 4-7 ((wid>>2)&1; SIMD
// assignment is wid%4, so each SIMD gets one wave per parity) process k-half1
// FIRST, then k-half0 (K-order commutes into acc). Each SIMD then has one
// wave reading while the other MFMAs -> LDS hides under MFMA.
__global__ __launch_bounds__(768, 2) void k_gemm(
    const float* __restrict__ tf, const float* __restrict__ sbm,
    const float* __restrict__ W1em, const unsigned short* __restrict__ W2t,
    const float* __restrict__ b2, const float* __restrict__ w3,
    float* __restrict__ partial) {
  __shared__ unsigned short As[2][16384];   // [buf][256 rows][64 k] swizzled
  __shared__ unsigned short Bs[2][16384];

  const int bid = blockIdx.x;
  const int swz = (bid & 7) * 128 + (bid >> 3);   // XCD swizzle (1024 % 8 == 0)
  const int bx = swz >> 2, by = swz & 3;
  const int row0 = bx << 8, col0 = by << 8;
  const int bb = row0 >> 9;                       // batch (256-row tile, no straddle)

  const int tid = threadIdx.x, lane = tid & 63, wid = tid >> 6;

  if (wid < 8) {
    // ================= CONSUMER =================
    const int wr = wid >> 2, wc = wid & 3;
    const int lm = lane & 15, lg = lane >> 4;
    const int aoff = (wr * 128 + lm) * 64;        // + m*1024 + s{0,1}
    const int boff = (wc * 64 + lm) * 64;         // + n*1024 + s{0,1}
    const int s0 = ((lg ^ (lm & 7)) << 3);        // k16 = lg
    const int s1 = (((4 + lg) ^ (lm & 7)) << 3);  // k16 = 4+lg
    // K-half stagger: waves 0-3 do h0 then h1; waves 4-7 do h1 then h0.
    const int ho = (wid >> 2) & 1;
    const int sF = ho ? s1 : s0;
    const int sS = ho ? s0 : s1;

    f32x4 acc[8][4];
#pragma unroll
    for (int m = 0; m < 8; ++m)
#pragma unroll
      for (int n = 0; n < 4; ++n) acc[m][n] = (f32x4){0.f, 0.f, 0.f, 0.f};

    __syncthreads();   // matches producer prologue (tile 0 ready)

#pragma unroll 1
    for (int t = 0; t < 16; ++t) {
      const unsigned short* Ad = As[t & 1];
      const unsigned short* Bd = Bs[t & 1];
      bf16x8 bkF[4], bkS[4];
      bf16x8 ap[2][2];   // rotating A-pair slots; all indices compile-time
      // ---- prologue: B first-half + first A pair
#pragma unroll
      for (int n = 0; n < 4; ++n) bkF[n] = *(const bf16x8*)(Bd + boff + n * 1024 + sF);
      ap[0][0] = *(const bf16x8*)(Ad + aoff + 0 * 1024 + sF);
      ap[0][1] = *(const bf16x8*)(Ad + aoff + 1 * 1024 + sF);
      __builtin_amdgcn_s_setprio(1);
#pragma unroll
      for (int G = 0; G < 8; ++G) {          // 8 groups of (2 m-rows x 4 n)
        const int half = G >> 2;             // 0: first half, 1: second half
        const int g = G & 3;
        const int cur = G & 1, nxt = cur ^ 1;
        // prefetch next group's A pair (crosses the half seam at G=3)
        if (G < 7) {
          const int Gn = G + 1;
          const int gn = Gn & 3;
          const int sN = (Gn >> 2) ? sS : sF;
          ap[nxt][0] = *(const bf16x8*)(Ad + aoff + (2 * gn) * 1024 + sN);
          ap[nxt][1] = *(const bf16x8*)(Ad + aoff + (2 * gn + 1) * 1024 + sN);
        }
        // issue B second-half one group before it's needed (8-MFMA distance)
        if (G == 3) {
#pragma unroll
          for (int n = 0; n < 4; ++n) bkS[n] = *(const bf16x8*)(Bd + boff + n * 1024 + sS);
        }
#pragma unroll
        for (int n = 0; n < 4; ++n)
          acc[2 * g][n] = __builtin_amdgcn_mfma_f32_16x16x32_bf16(
              ap[cur][0], half ? bkS[n] : bkF[n], acc[2 * g][n], 0, 0, 0);
#pragma unroll
        for (int n = 0; n < 4; ++n)
          acc[2 * g + 1][n] = __builtin_amdgcn_mfma_f32_16x16x32_bf16(
              ap[cur][1], half ? bkS[n] : bkF[n], acc[2 * g + 1][n], 0, 0, 0);
      }
      __builtin_amdgcn_s_setprio(0);
      __syncthreads();   // tile boundary (consumer: vm=0, lgkm drained by MFMA use)
    }

    // ---- epilogue: partial[row][by*4+wc] = sum_cols relu(acc + b2[col]) * w3[col]
    float b2v[4], w3v[4];
#pragma unroll
    for (int n = 0; n < 4; ++n) {
      const int col = col0 + wc * 64 + n * 16 + lm;
      b2v[n] = b2[col];
      w3v[n] = w3[col];
    }
#pragma unroll
    for (int m = 0; m < 8; ++m) {
#pragma unroll
      for (int r = 0; r < 4; ++r) {
        float v = 0.f;
#pragma unroll
        for (int n = 0; n < 4; ++n) {
          float h = acc[m][n][r] + b2v[n];
          h = fmaxf(h, 0.f);
          v += h * w3v[n];
        }
        v += __shfl_xor(v, 1, 16);
        v += __shfl_xor(v, 2, 16);
        v += __shfl_xor(v, 4, 16);
        v += __shfl_xor(v, 8, 16);
        if (lm == 0)
          partial[(size_t)(row0 + wr * 128 + m * 16 + lg * 4 + r) * 16 + by * 4 + wc] = v;
      }
    }
  } else {
    // ================= PRODUCER =================
    const int pt = tid - 512;               // 0..255
    const int pw = pt >> 6;                 // producer wave 0..3
    const int pc = (pt & 7) << 3;           // 8-col block within K-tile
    const int prb = pt >> 3;                // 0..31; rows prb + 32j
    const int aph = (((pt & 7) ^ (prb & 7)) << 3);   // swizzled chunk (elems)
    // B staging: per l, row = l*32 + pw*8 + (lane>>3); pre-swizzled source col
    const int brow = (pw << 3) + (lane >> 3);
    const int bscol = (((lane & 7) ^ ((lane >> 3) & 7)) << 3);

    // tf rows -> registers (8 rows x 5)
    float ptf[8][5];
#pragma unroll
    for (int j = 0; j < 8; ++j) {
      const float* f = tf + (size_t)(row0 + prb + 32 * j) * 5;
#pragma unroll
      for (int i = 0; i < 5; ++i) ptf[j][i] = f[i];
    }

    const float* sbp = sbm + (size_t)bb * 1024;

#define PRODUCE(kt, d)                                                         \
    {                                                                          \
      _Pragma("unroll")                                                        \
      for (int l = 0; l < 8; ++l)                                              \
        __builtin_amdgcn_global_load_lds(                                      \
            (const __attribute__((address_space(1))) void*)(                   \
                W2t + (size_t)(col0 + l * 32 + brow) * 1024 + (kt) * 64 + bscol), \
            (__attribute__((address_space(3))) void*)(                         \
                Bs[d] + (l * 32 + (pw << 3)) * 64), 16, 0, 0);                 \
      const int kb = (kt) * 64 + pc;                                           \
      const float4 sa = *(const float4*)(sbp + kb);                            \
      const float4 sbv = *(const float4*)(sbp + kb + 4);                       \
      float4 wa[5], wb[5];                                                     \
      _Pragma("unroll")                                                        \
      for (int i = 0; i < 5; ++i) {                                            \
        wa[i] = *(const float4*)(W1em + i * 1024 + kb);                        \
        wb[i] = *(const float4*)(W1em + i * 1024 + kb + 4);                    \
      }                                                                        \
      _Pragma("unroll")                                                        \
      for (int j = 0; j < 8; ++j) {                                            \
        const float f0 = ptf[j][0], f1 = ptf[j][1], f2 = ptf[j][2],            \
                    f3 = ptf[j][3], f4 = ptf[j][4];                            \
        float h0 = fmaf(f4, wa[4].x, fmaf(f3, wa[3].x, fmaf(f2, wa[2].x, fmaf(f1, wa[1].x, fmaf(f0, wa[0].x, sa.x))))); \
        float h1 = fmaf(f4, wa[4].y, fmaf(f3, wa[3].y, fmaf(f2, wa[2].y, fmaf(f1, wa[1].y, fmaf(f0, wa[0].y, sa.y))))); \
        float h2 = fmaf(f4, wa[4].z, fmaf(f3, wa[3].z, fmaf(f2, wa[2].z, fmaf(f1, wa[1].z, fmaf(f0, wa[0].z, sa.z))))); \
        float h3 = fmaf(f4, wa[4].w, fmaf(f3, wa[3].w, fmaf(f2, wa[2].w, fmaf(f1, wa[1].w, fmaf(f0, wa[0].w, sa.w))))); \
        float h4 = fmaf(f4, wb[4].x, fmaf(f3, wb[3].x, fmaf(f2, wb[2].x, fmaf(f1, wb[1].x, fmaf(f0, wb[0].x, sbv.x))))); \
        float h5 = fmaf(f4, wb[4].y, fmaf(f3, wb[3].y, fmaf(f2, wb[2].y, fmaf(f1, wb[1].y, fmaf(f0, wb[0].y, sbv.y))))); \
        float h6 = fmaf(f4, wb[4].z, fmaf(f3, wb[3].z, fmaf(f2, wb[2].z, fmaf(f1, wb[1].z, fmaf(f0, wb[0].z, sbv.z))))); \
        float h7 = fmaf(f4, wb[4].w, fmaf(f3, wb[3].w, fmaf(f2, wb[2].w, fmaf(f1, wb[1].w, fmaf(f0, wb[0].w, sbv.w))))); \
        h0 = fmaxf(h0, 0.f); h1 = fmaxf(h1, 0.f); h2 = fmaxf(h2, 0.f); h3 = fmaxf(h3, 0.f); \
        h4 = fmaxf(h4, 0.f); h5 = fmaxf(h5, 0.f); h6 = fmaxf(h6, 0.f); h7 = fmaxf(h7, 0.f); \
        uint4 pk;                                                              \
        pk.x = cvt_pk_bf16(h0, h1);                                            \
        pk.y = cvt_pk_bf16(h2, h3);                                            \
        pk.z = cvt_pk_bf16(h4, h5);                                            \
        pk.w = cvt_pk_bf16(h6, h7);                                            \
        *(uint4*)&As[d][(prb + 32 * j) * 64 + aph] = pk;                       \
      }                                                                        \
    }

    PRODUCE(0, 0);
    __syncthreads();   // vm+lgkm drained by syncthreads semantics; tile 0 ready
#pragma unroll 1
    for (int t = 0; t < 16; ++t) {
      if (t < 15) PRODUCE(t + 1, (t + 1) & 1);
      __syncthreads();
    }
#undef PRODUCE
  }
}

// ---------------- k_softmax: fused utils-reduction + nested-logit softmax
__global__ __launch_bounds__(256) void k_softmax(
    const float* __restrict__ partial, const float* __restrict__ b3,
    const int* __restrict__ nids, const int* __restrict__ mask,
    const float* __restrict__ etas, float* __restrict__ utils_out,
    float* __restrict__ p_task, float* __restrict__ p_nest) {
  const int b = blockIdx.x, tid = threadIdx.x;
  const int lane = tid & 63, wv = tid >> 6;
  __shared__ float smax[4][4];
  __shared__ int scnt[4][4];
  __shared__ float ssum[4][4];
  __shared__ float sred[4];
  __shared__ int sredi[4];

  const size_t base = (size_t)b * 512;
  const float b3v = b3[0];
  float uraw[2];
#pragma unroll
  for (int k = 0; k < 2; ++k) {
    const size_t row = base + tid + k * 256;
    const float4* p = (const float4*)(partial + row * 16);
    const float4 pa = p[0], pb = p[1], pc = p[2], pd = p[3];
    uraw[k] = b3v + pa.x + pa.y + pa.z + pa.w + pb.x + pb.y + pb.z + pb.w +
              pc.x + pc.y + pc.z + pc.w + pd.x + pd.y + pd.z + pd.w;
  }
  const int n0 = nids[base + tid], n1 = nids[base + 256 + tid];
  const bool m0 = mask[base + tid] != 0, m1 = mask[base + 256 + tid] != 0;
  const float u0 = m0 ? uraw[0] : NEGV;
  const float u1 = m1 ? uraw[1] : NEGV;
  utils_out[base + tid] = u0;
  utils_out[base + 256 + tid] = u1;
  const float eta[4] = {etas[0], etas[1], etas[2], etas[3]};

  float lmax[4]; int lcnt[4];
#pragma unroll
  for (int m = 0; m < 4; ++m) {
    const bool e0 = m0 && (n0 == m), e1 = m1 && (n1 == m);
    lmax[m] = fmaxf(e0 ? u0 : -INFINITY, e1 ? u1 : -INFINITY);
    lcnt[m] = (int)e0 + (int)e1;
  }
#pragma unroll
  for (int m = 0; m < 4; ++m)
#pragma unroll
    for (int off = 32; off >= 1; off >>= 1) {
      lmax[m] = fmaxf(lmax[m], __shfl_xor(lmax[m], off));
      lcnt[m] += __shfl_xor(lcnt[m], off);
    }
  if (lane == 0) {
#pragma unroll
    for (int m = 0; m < 4; ++m) { smax[wv][m] = lmax[m]; scnt[wv][m] = lcnt[m]; }
  }
  __syncthreads();
  float mval[4]; bool ne[4];
#pragma unroll
  for (int m = 0; m < 4; ++m) {
    const float mx = fmaxf(fmaxf(smax[0][m], smax[1][m]), fmaxf(smax[2][m], smax[3][m]));
    const int c = scnt[0][m] + scnt[1][m] + scnt[2][m] + scnt[3][m];
    ne[m] = c > 0;
    mval[m] = ne[m] ? mx : 0.f;
  }
  float lsum[4];
#pragma unroll
  for (int m = 0; m < 4; ++m) {
    float s = 0.f;
    if (m0 && n0 == m) s += expf((u0 - mval[m]) / eta[m]);
    if (m1 && n1 == m) s += expf((u1 - mval[m]) / eta[m]);
    lsum[m] = s;
  }
#pragma unroll
  for (int m = 0; m < 4; ++m)
#pragma unroll
    for (int off = 32; off >= 1; off >>= 1) lsum[m] += __shfl_xor(lsum[m], off);
  if (lane == 0) {
#pragma unroll
    for (int m = 0; m < 4; ++m) ssum[wv][m] = lsum[m];
  }
  __syncthreads();
  float sums[4], U[4];
#pragma unroll
  for (int m = 0; m < 4; ++m) {
    const float s = ssum[0][m] + ssum[1][m] + ssum[2][m] + ssum[3][m];
    sums[m] = fmaxf(s, EPSV);
    U[m] = ne[m] ? (mval[m] + eta[m] * logf(sums[m])) : NEGV;
  }
  const float mU = fmaxf(fmaxf(U[0], U[1]), fmaxf(U[2], U[3]));
  float pe[4], pes = 0.f;
#pragma unroll
  for (int m = 0; m < 4; ++m) { pe[m] = expf(U[m] - mU); pes += pe[m]; }
  float pn[4];
#pragma unroll
  for (int m = 0; m < 4; ++m) pn[m] = pe[m] / pes;
  if (tid == 0) {
#pragma unroll
    for (int m = 0; m < 4; ++m) p_nest[(size_t)b * 4 + m] = pn[m];
  }
  float pt[2];
  const float uu[2] = {u0, u1};
  const int nn[2] = {n0, n1};
  const bool mm[2] = {m0, m1};
#pragma unroll
  for (int k = 0; k < 2; ++k) {
    const bool valid = mm[k] && nn[k] >= 0 && nn[k] < 4;
    float mt = 0.f, st = 1.f, pnt = 0.f, et = 1.f;
#pragma unroll
    for (int m = 0; m < 4; ++m)
      if (nn[k] == m) { mt = mval[m]; st = sums[m]; pnt = pn[m]; et = eta[m]; }
    pt[k] = valid ? pnt * expf((uu[k] - mt) / et) / st : 0.f;
  }
  float lp = pt[0] + pt[1];
  int lmk = (int)m0 + (int)m1;
#pragma unroll
  for (int off = 32; off >= 1; off >>= 1) {
    lp += __shfl_xor(lp, off);
    lmk += __shfl_xor(lmk, off);
  }
  if (lane == 0) { sred[wv] = lp; sredi[wv] = lmk; }
  __syncthreads();
  const float sumpt = sred[0] + sred[1] + sred[2] + sred[3];
  const int nmask = sredi[0] + sredi[1] + sredi[2] + sredi[3];
  const bool fallback = (nmask > 0) && (sumpt <= EPSV);
  if (fallback) {
    const float uni = 1.f / (float)(nmask > 0 ? nmask : 1);
    pt[0] = m0 ? uni : pt[0];
    pt[1] = m1 ? uni : pt[1];
  }
  p_task[base + tid] = pt[0];
  p_task[base + 256 + tid] = pt[1];
}

extern "C" void kernel_launch(void* const* d_in, const int* in_sizes, int n_in,
                              void* d_out, int out_size, void* d_ws, size_t ws_size,
                              hipStream_t stream) {
  const float* state = (const float*)d_in[0];
  const float* tf = (const float*)d_in[1];
  const int* nids = (const int*)d_in[2];
  const int* mask = (const int*)d_in[3];
  const float* emb_w = (const float*)d_in[4];
  const float* emb_b = (const float*)d_in[5];
  const float* w1 = (const float*)d_in[6];
  const float* b1 = (const float*)d_in[7];
  const float* w2 = (const float*)d_in[8];
  const float* b2 = (const float*)d_in[9];
  const float* w3 = (const float*)d_in[10];
  const float* b3 = (const float*)d_in[11];
  const float* etas = (const float*)d_in[12];

  float* out = (float*)d_out;
  float* utils_out = out;            // 65536
  float* p_task = out + 65536;       // 65536
  float* p_nest = out + 131072;      // 512

  char* ws = (char*)d_ws;
  unsigned short* W2t = (unsigned short*)ws; ws += 1024ull * 1024 * 2;    // 2 MB
  float* partial = (float*)ws;               ws += 65536ull * 16 * 4;     // 4 MB
  float* W1e = (float*)ws;                   ws += 5 * 1024 * 4;
  float* sb = (float*)ws;                    ws += 128 * 1024 * 4;

  k_prep<<<772, 256, 0, stream>>>(state, w1, b1, emb_w, emb_b, w2, W1e, sb, W2t);
  k_gemm<<<1024, 768, 0, stream>>>(tf, sb, W1e, W2t, b2, w3, partial);
  k_softmax<<<128, 256, 0, stream>>>(partial, b3, nids, mask, etas,
                                     utils_out, p_task, p_nest);
}